// Round 5
// baseline (141.638 us; speedup 1.0000x reference)
//
#include <hip/hip_runtime.h>
#include <math.h>

// loss = -sum_ij d1[i,j] * log(d2[i,j] + 1e-5), fp32 in, scalar fp32 out.
//
// Session model (R0-R4):
//  - Reduction tree FROZEN (absmax 0.0): thread t owns elements t + p*STRIDE,
//    p=0..7, acc by component, wave shuffle, 4-wave LDS combine, partials[blk].
//  - R2: software MLP depth alone changed nothing on the pure-VGPR path.
//  - R3: sc0 sc1 nt on loads = -16% (44.9 -> 37.7 us). Mechanism: harness
//    re-poison leaves inputs DIRTY in L3; allocate-on-read evicted dirty
//    lines -> ~64 MB concurrent HBM writeback on a read-only kernel.
//  - R4: splitting the streams over the two read-return paths (d2 via
//    global_load_lds TA->LDS direct, d1 via VGPR-return) = -18% (-> ~31 us,
//    4.3 TB/s effective). Paths are at least partly independent.
// R5: (a) give the LDS path the same no-allocate policy via aux=19
//     (SC0=1 | NT=2 | SC1=16 on gfx94x/gfx950) - R4 left d2 allocating,
//     so half the writeback cascade was still live; (b) 8 write-once LDS
//     slots (32 KB/block) instead of a 4-slot ring - removes the
//     ds_read+lgkmcnt(0) drain from the refill path entirely; all 16 VMEM
//     ops issued up front (16 KB/wave in flight), drained vmcnt(14..0).

#define EPS 1e-5f
#define BLOCK 256
#define GRID 2048                 // GRID*BLOCK*8 == n4 exactly
#define STRIDE (GRID * BLOCK)     // float4 stride between a thread's windows

typedef float f4v __attribute__((ext_vector_type(4)));

#define AS1 __attribute__((address_space(1)))
#define AS3 __attribute__((address_space(3)))

#define CPOL_NT 19   // SC0(1) | NT(2) | SC1(16): bypass + no-allocate

// d1 load on the VGPR-return path, L2-bypass + non-temporal.
#define LOADX(X, PA)                                                 \
    asm volatile("global_load_dwordx4 %0, %1, off sc0 sc1 nt"        \
                 : "=&v"(X) : "v"(PA) : "memory")

// Hand-counted vmem wait + scheduling fence (rule #18).
#define WAITV(N)                                              \
    do {                                                      \
        asm volatile("s_waitcnt vmcnt(" #N ")" ::: "memory"); \
        __builtin_amdgcn_sched_barrier(0);                    \
    } while (0)

// Same element->acc mapping and fma contraction as the baseline.
#define CP(X, Y)                                              \
    do {                                                      \
        acc0 = fmaf((X).x, __logf((Y).x + EPS), acc0);        \
        acc1 = fmaf((X).y, __logf((Y).y + EPS), acc1);        \
        acc2 = fmaf((X).z, __logf((Y).z + EPS), acc2);        \
        acc3 = fmaf((X).w, __logf((Y).w + EPS), acc3);        \
    } while (0)

__global__ __launch_bounds__(BLOCK) void cep_loss_kernel(
        const f4v* __restrict__ d1,
        const f4v* __restrict__ d2,
        float* __restrict__ partials) {
    // 8 write-once staging slots: 8 x 256 x 16B = 32 KB/block
    // -> 5 blocks/CU (160 KB LDS pool) = 20 waves/CU.
    __shared__ f4v sB[8][BLOCK];

    const int tid = blockIdx.x * BLOCK + threadIdx.x;
    const int wb  = threadIdx.x & ~63;   // wave-uniform LDS slot base
    const f4v* pa = d1 + tid;
    const f4v* pb = d2 + tid;

    float acc0 = 0.0f, acc1 = 0.0f, acc2 = 0.0f, acc3 = 0.0f;
    f4v x0, x1, x2, x3, x4, x5, x6, x7;

    // One stage: d2 -> LDS-direct (wave-uniform dest base, HW adds lane*16;
    // per-lane global src; nt no-allocate policy), d1 -> VGPR path.
#define ISSUE(P, X)                                                      \
    do {                                                                 \
        __builtin_amdgcn_global_load_lds(                                \
            (const AS1 void*)pb, (AS3 void*)&sB[P][wb], 16, 0, CPOL_NT); \
        LOADX(X, pa);                                                    \
        pb += STRIDE; pa += STRIDE;                                      \
    } while (0)

    // Issue everything: 16 dwordx4 (16 KB/wave) in flight, no refill loop.
    ISSUE(0, x0); ISSUE(1, x1); ISSUE(2, x2); ISSUE(3, x3);
    ISSUE(4, x4); ISSUE(5, x5); ISSUE(6, x6); ISSUE(7, x7);

    f4v y;
    // Drain oldest-first: stage p complete when vmcnt <= 14-2p.
    WAITV(14); y = sB[0][threadIdx.x]; CP(x0, y);
    WAITV(12); y = sB[1][threadIdx.x]; CP(x1, y);
    WAITV(10); y = sB[2][threadIdx.x]; CP(x2, y);
    WAITV(8);  y = sB[3][threadIdx.x]; CP(x3, y);
    WAITV(6);  y = sB[4][threadIdx.x]; CP(x4, y);
    WAITV(4);  y = sB[5][threadIdx.x]; CP(x5, y);
    WAITV(2);  y = sB[6][threadIdx.x]; CP(x6, y);
    WAITV(0);  y = sB[7][threadIdx.x]; CP(x7, y);

    float acc = (acc0 + acc1) + (acc2 + acc3);

    // Wave-64 shuffle reduction (identical tree to baseline).
    #pragma unroll
    for (int off = 32; off > 0; off >>= 1)
        acc += __shfl_down(acc, off, 64);

    __shared__ float wave_sums[BLOCK / 64];
    int lane = threadIdx.x & 63;
    int wid  = threadIdx.x >> 6;
    if (lane == 0) wave_sums[wid] = acc;
    __syncthreads();

    if (threadIdx.x == 0) {
        float s = wave_sums[0] + wave_sums[1] + wave_sums[2] + wave_sums[3];
        partials[blockIdx.x] = s;  // deterministic: no atomics
    }
}

__global__ __launch_bounds__(BLOCK) void cep_final_kernel(
        const float* __restrict__ partials, float* __restrict__ out, int nparts) {
    float acc = 0.0f;
    for (int i = threadIdx.x; i < nparts; i += BLOCK)
        acc += partials[i];

    #pragma unroll
    for (int off = 32; off > 0; off >>= 1)
        acc += __shfl_down(acc, off, 64);

    __shared__ float wave_sums[BLOCK / 64];
    int lane = threadIdx.x & 63;
    int wid  = threadIdx.x >> 6;
    if (lane == 0) wave_sums[wid] = acc;
    __syncthreads();

    if (threadIdx.x == 0) {
        float s = wave_sums[0] + wave_sums[1] + wave_sums[2] + wave_sums[3];
        out[0] = -s;
    }
}

extern "C" void kernel_launch(void* const* d_in, const int* in_sizes, int n_in,
                              void* d_out, int out_size, void* d_ws, size_t ws_size,
                              hipStream_t stream) {
    const f4v* d1 = (const f4v*)d_in[0];
    const f4v* d2 = (const f4v*)d_in[1];
    float* out      = (float*)d_out;
    float* partials = (float*)d_ws;

    // n = 4096*4096 floats -> n4 = 4,194,304 float4. GRID*BLOCK*8 == n4.
    cep_loss_kernel<<<GRID, BLOCK, 0, stream>>>(d1, d2, partials);
    cep_final_kernel<<<1, BLOCK, 0, stream>>>(partials, out, GRID);
}

// Round 6
// 136.192 us; speedup vs baseline: 1.0400x; 1.0400x over previous
//
#include <hip/hip_runtime.h>
#include <math.h>

// loss = -sum_ij d1[i,j] * log(d2[i,j] + 1e-5), fp32 in, scalar fp32 out.
//
// Session model (R0-R5):
//  - Reduction tree FROZEN (absmax 0.0): thread t owns elements t + p*STRIDE,
//    p=0..7, acc by component, wave shuffle, 4-wave LDS combine, partials[blk].
//  - R2: software MLP depth alone changed nothing on the pure-VGPR path.
//  - R3: sc0 sc1 nt on d1 VGPR loads = -16%. Both inputs are ~50% L3-dirty
//    (FETCH == 65.5 MB == half of demand all session); no-allocate stops the
//    read-allocations from evicting the other stream's dirty lines.
//  - R4: splitting streams over the two read-return paths (d2 via
//    global_load_lds, d1 via VGPR) = -18% -> ~31 us, 4.3 TB/s effective.
//  - R5 REGRESSION (confounded): aux=19 (SC0|NT|SC1 bypass) on the LDS path
//    + 8-slot write-once. Suspect: bypass skips L3 lookup -> d2's ~50% dirty
//    L3 hits became HBM round-trips. Lesson (pending confirm): only nt the
//    stream that already misses; NEVER bypass the cache-resident stream.
// R6: de-confound = R5 structure with aux=0 (R4's policy exactly).
//     Single diff vs R5: cpol. Single diff vs R4: write-once 8-slot issue
//     (all 16 VMEM ops up front, vmcnt(14..0) drain, no lgkm serialization).

#define EPS 1e-5f
#define BLOCK 256
#define GRID 2048                 // GRID*BLOCK*8 == n4 exactly
#define STRIDE (GRID * BLOCK)     // float4 stride between a thread's windows

typedef float f4v __attribute__((ext_vector_type(4)));

#define AS1 __attribute__((address_space(1)))
#define AS3 __attribute__((address_space(3)))

// d1 load on the VGPR-return path, L2-bypass + non-temporal (R3 win: d1's
// misses shouldn't allocate/evict; proven -16%).
#define LOADX(X, PA)                                                 \
    asm volatile("global_load_dwordx4 %0, %1, off sc0 sc1 nt"        \
                 : "=&v"(X) : "v"(PA) : "memory")

// Hand-counted vmem wait + scheduling fence (rule #18).
#define WAITV(N)                                              \
    do {                                                      \
        asm volatile("s_waitcnt vmcnt(" #N ")" ::: "memory"); \
        __builtin_amdgcn_sched_barrier(0);                    \
    } while (0)

// Same element->acc mapping and fma contraction as the baseline.
#define CP(X, Y)                                              \
    do {                                                      \
        acc0 = fmaf((X).x, __logf((Y).x + EPS), acc0);        \
        acc1 = fmaf((X).y, __logf((Y).y + EPS), acc1);        \
        acc2 = fmaf((X).z, __logf((Y).z + EPS), acc2);        \
        acc3 = fmaf((X).w, __logf((Y).w + EPS), acc3);        \
    } while (0)

__global__ __launch_bounds__(BLOCK) void cep_loss_kernel(
        const f4v* __restrict__ d1,
        const f4v* __restrict__ d2,
        float* __restrict__ partials) {
    // 8 write-once staging slots: 8 x 256 x 16B = 32 KB/block
    // -> 5 blocks/CU; in-flight ops/CU still higher than R4 (320 vs 256).
    __shared__ f4v sB[8][BLOCK];

    const int tid = blockIdx.x * BLOCK + threadIdx.x;
    const int wb  = threadIdx.x & ~63;   // wave-uniform LDS slot base
    const f4v* pa = d1 + tid;
    const f4v* pb = d2 + tid;

    float acc0 = 0.0f, acc1 = 0.0f, acc2 = 0.0f, acc3 = 0.0f;
    f4v x0, x1, x2, x3, x4, x5, x6, x7;

    // One stage: d2 -> LDS-direct, DEFAULT policy (aux=0: allocate, keep the
    // ~50% dirty-L3 hits); d1 -> VGPR path with nt.
#define ISSUE(P, X)                                                      \
    do {                                                                 \
        __builtin_amdgcn_global_load_lds(                                \
            (const AS1 void*)pb, (AS3 void*)&sB[P][wb], 16, 0, 0);       \
        LOADX(X, pa);                                                    \
        pb += STRIDE; pa += STRIDE;                                      \
    } while (0)

    // Issue everything: 16 dwordx4 (16 KB/wave) in flight, no refill loop.
    ISSUE(0, x0); ISSUE(1, x1); ISSUE(2, x2); ISSUE(3, x3);
    ISSUE(4, x4); ISSUE(5, x5); ISSUE(6, x6); ISSUE(7, x7);

    f4v y;
    // Drain oldest-first: stage p complete when vmcnt <= 14-2p.
    WAITV(14); y = sB[0][threadIdx.x]; CP(x0, y);
    WAITV(12); y = sB[1][threadIdx.x]; CP(x1, y);
    WAITV(10); y = sB[2][threadIdx.x]; CP(x2, y);
    WAITV(8);  y = sB[3][threadIdx.x]; CP(x3, y);
    WAITV(6);  y = sB[4][threadIdx.x]; CP(x4, y);
    WAITV(4);  y = sB[5][threadIdx.x]; CP(x5, y);
    WAITV(2);  y = sB[6][threadIdx.x]; CP(x6, y);
    WAITV(0);  y = sB[7][threadIdx.x]; CP(x7, y);

    float acc = (acc0 + acc1) + (acc2 + acc3);

    // Wave-64 shuffle reduction (identical tree to baseline).
    #pragma unroll
    for (int off = 32; off > 0; off >>= 1)
        acc += __shfl_down(acc, off, 64);

    __shared__ float wave_sums[BLOCK / 64];
    int lane = threadIdx.x & 63;
    int wid  = threadIdx.x >> 6;
    if (lane == 0) wave_sums[wid] = acc;
    __syncthreads();

    if (threadIdx.x == 0) {
        float s = wave_sums[0] + wave_sums[1] + wave_sums[2] + wave_sums[3];
        partials[blockIdx.x] = s;  // deterministic: no atomics
    }
}

__global__ __launch_bounds__(BLOCK) void cep_final_kernel(
        const float* __restrict__ partials, float* __restrict__ out, int nparts) {
    float acc = 0.0f;
    for (int i = threadIdx.x; i < nparts; i += BLOCK)
        acc += partials[i];

    #pragma unroll
    for (int off = 32; off > 0; off >>= 1)
        acc += __shfl_down(acc, off, 64);

    __shared__ float wave_sums[BLOCK / 64];
    int lane = threadIdx.x & 63;
    int wid  = threadIdx.x >> 6;
    if (lane == 0) wave_sums[wid] = acc;
    __syncthreads();

    if (threadIdx.x == 0) {
        float s = wave_sums[0] + wave_sums[1] + wave_sums[2] + wave_sums[3];
        out[0] = -s;
    }
}

extern "C" void kernel_launch(void* const* d_in, const int* in_sizes, int n_in,
                              void* d_out, int out_size, void* d_ws, size_t ws_size,
                              hipStream_t stream) {
    const f4v* d1 = (const f4v*)d_in[0];
    const f4v* d2 = (const f4v*)d_in[1];
    float* out      = (float*)d_out;
    float* partials = (float*)d_ws;

    // n = 4096*4096 floats -> n4 = 4,194,304 float4. GRID*BLOCK*8 == n4.
    cep_loss_kernel<<<GRID, BLOCK, 0, stream>>>(d1, d2, partials);
    cep_final_kernel<<<1, BLOCK, 0, stream>>>(partials, out, GRID);
}